// Round 3
// baseline (436.944 us; speedup 1.0000x reference)
//
#include <hip/hip_runtime.h>
#include <hip/hip_bf16.h>

// B=8, H=W=128, C=F=256, 3x3 modulated conv (StyleGAN2 style), bf16 MFMA implicit GEMM.
// R2: plane-major LDS (conflict-free ds_read_b128) + global_load_lds(16B) staging +
//     B double-buffer (10 barriers/chunk vs 18) + XCD-locality block swizzle.
// R3: fix bf16 conversion (union pun via __float2bfloat16; no .data member in this ROCm).

#define NB 8
#define NH 128
#define NW 128
#define NC 256
#define NF 256

typedef __attribute__((ext_vector_type(8))) short bf16x8;
typedef __attribute__((ext_vector_type(4))) float f32x4;

// A: 3 rows(dh) x 4 planes(c-quad) x 130 chunks(w+halo) x 16B, plane pitch 2080B (8 mod 32 dwords)
#define PA 2080
#define A_ROW (4 * PA)          // 8320
#define A_BYTES (3 * A_ROW)     // 24960
// B: 2 bufs x 4 planes x 128 chunks(f) x 16B, padded plane pitch 2080B
#define B_BUF (4 * PA)          // 8320
#define LDS_BYTES (A_BYTES + 2 * B_BUF)  // 41600

__device__ __forceinline__ ushort f2bf(float v) {
    union { ushort u; __hip_bfloat16 h; } o;
    o.h = __float2bfloat16(v);
    return o.u;
}

__device__ __forceinline__ void gload16(const ushort* g, const char* l) {
    __builtin_amdgcn_global_load_lds(
        (const __attribute__((address_space(1))) void*)g,
        (__attribute__((address_space(3))) void*)l,
        16, 0, 0);
}

// ---------------- x fp32 -> bf16 (8 elems/thread, 16B stores) ----------------
__global__ void k_cvt(const float* __restrict__ x, ushort* __restrict__ xbf) {
    size_t i = ((size_t)blockIdx.x * 256 + threadIdx.x) * 8;
    float4 a = *(const float4*)(x + i);
    float4 b = *(const float4*)(x + i + 4);
    union { ushort s[8]; uint4 u; } o;
    o.s[0] = f2bf(a.x); o.s[1] = f2bf(a.y);
    o.s[2] = f2bf(a.z); o.s[3] = f2bf(a.w);
    o.s[4] = f2bf(b.x); o.s[5] = f2bf(b.y);
    o.s[6] = f2bf(b.z); o.s[7] = f2bf(b.w);
    *(uint4*)(xbf + i) = o.u;
}

// ---------------- modulate + demodulate weights ----------------
// One block per (b,f), 256 threads (one per c). wm layout [b][tap][f][c] bf16.
__global__ void k_modw(const float* __restrict__ kern, const float* __restrict__ style,
                       ushort* __restrict__ wm) {
    int b = blockIdx.x >> 8;
    int f = blockIdx.x & 255;
    int c = threadIdx.x;
    float s = style[b * 256 + c] + 1.0f;
    float w[9];
    float acc = 0.f;
#pragma unroll
    for (int t = 0; t < 9; ++t) {
        w[t] = kern[(t * 256 + c) * 256 + f] * s;
        acc += w[t] * w[t];
    }
#pragma unroll
    for (int off = 32; off; off >>= 1) acc += __shfl_down(acc, off);
    __shared__ float part[4];
    if ((threadIdx.x & 63) == 0) part[threadIdx.x >> 6] = acc;
    __syncthreads();
    float total = part[0] + part[1] + part[2] + part[3];
    float inv = 1.0f / sqrtf(total + 1e-8f);
#pragma unroll
    for (int t = 0; t < 9; ++t) {
        wm[(((b * 9 + t) * 256 + f) * 256) + c] = f2bf(w[t] * inv);
    }
}

// ---------------- conv as implicit GEMM ----------------
__global__ void __launch_bounds__(256)
k_conv(const ushort* __restrict__ xbf, const ushort* __restrict__ wm,
       float* __restrict__ out) {
    // XCD-locality swizzle: b = bidx%8 pins each image to one XCD (round-robin dispatch heuristic)
    const int bidx = blockIdx.x;
    const int b    = bidx & 7;
    const int rest = bidx >> 3;       // 0..255
    const int fh   = rest & 1;
    const int h    = rest >> 1;       // 0..127

    __shared__ __align__(16) char smem[LDS_BYTES];
    char* As = smem;                  // 3 x 4 x 130 x 16B
    char* Bs = smem + A_BYTES;        // 2 bufs x 4 x 128 x 16B (padded pitch)

    const int tid = threadIdx.x;
    const int wave = tid >> 6, lane = tid & 63;
    const int wm_ = wave & 1, wn_ = wave >> 1;   // 2x2 wave grid, each 64x64
    const int lrow = lane & 15;
    const int quad = lane >> 4;

    // Zero all of As once (covers halo chunks s=0/129 and out-of-image rows).
    {
        const uint4 z = {0, 0, 0, 0};
        for (int i = tid; i < A_BYTES / 16; i += 256) ((uint4*)As)[i] = z;
    }
    __syncthreads();  // zeroing complete before any DMA staging lands

    f32x4 acc[4][4];
    const f32x4 zero4 = {0.f, 0.f, 0.f, 0.f};
#pragma unroll
    for (int mi = 0; mi < 4; ++mi)
#pragma unroll
        for (int ni = 0; ni < 4; ++ni) acc[mi][ni] = zero4;

    const ushort* xb_base = xbf + (size_t)b * 128 * 128 * 256;
    const ushort* wm_base = wm + ((size_t)b * 9) * 256 * 256 + (size_t)fh * 128 * 256;

    for (int c0 = 0; c0 < 256; c0 += 32) {
        // ---- stage A for this chunk: 24 wave-loads of 64x16B, 6 per wave ----
#pragma unroll
        for (int i = 0; i < 6; ++i) {
            int L = wave * 6 + i;            // wave-uniform
            int dh = L >> 3, rem = L & 7;
            int p = rem >> 1, half = rem & 1;
            int hp = h + dh - 1;
            if (hp >= 0 && hp < 128) {       // wave-uniform branch
                int w = half * 64 + lane;
                const ushort* g = xb_base + ((size_t)hp * 128 + w) * 256 + c0 + p * 8;
                const char* l = As + dh * A_ROW + p * PA + 16 + half * 1024;
                gload16(g, l);
            }
        }
        // ---- stage B tap0 into buf0 ----
        {
#pragma unroll
            for (int i = 0; i < 2; ++i) {
                int s = wave * 2 + i;
                int p = s >> 1, halfp = s & 1;
                int f = halfp * 64 + lane;
                const ushort* g = wm_base + ((size_t)(0 * 256) + f) * 256 + c0 + p * 8;
                const char* l = Bs + p * PA + halfp * 1024;
                gload16(g, l);
            }
        }
        __syncthreads();  // A + B0 resident

#pragma unroll
        for (int tap = 0; tap < 9; ++tap) {
            const int dh = tap / 3, dw = tap % 3;
            const int cur = tap & 1;
            // prefetch next tap's B into the other buffer
            if (tap < 8) {
                int nxt = (tap + 1) & 1;
#pragma unroll
                for (int i = 0; i < 2; ++i) {
                    int s = wave * 2 + i;
                    int p = s >> 1, halfp = s & 1;
                    int f = halfp * 64 + lane;
                    const ushort* g = wm_base + ((size_t)((tap + 1) * 256) + f) * 256 + c0 + p * 8;
                    const char* l = Bs + nxt * B_BUF + p * PA + halfp * 1024;
                    gload16(g, l);
                }
            }
            // ---- fragments + MFMA ----
            bf16x8 af[4], bfr[4];
#pragma unroll
            for (int ni = 0; ni < 4; ++ni) {
                int f = wn_ * 64 + ni * 16 + lrow;
                bfr[ni] = *(const bf16x8*)(Bs + cur * B_BUF + quad * PA + f * 16);
            }
#pragma unroll
            for (int mi = 0; mi < 4; ++mi) {
                int s = wm_ * 64 + mi * 16 + lrow + dw;   // halo coord
                af[mi] = *(const bf16x8*)(As + dh * A_ROW + quad * PA + s * 16);
            }
#pragma unroll
            for (int mi = 0; mi < 4; ++mi)
#pragma unroll
                for (int ni = 0; ni < 4; ++ni)
                    acc[mi][ni] = __builtin_amdgcn_mfma_f32_16x16x32_bf16(
                        af[mi], bfr[ni], acc[mi][ni], 0, 0, 0);
            __syncthreads();  // B[cur] reads done; DMA for B[nxt] drained (vmcnt at barrier)
        }
    }

    // ---- epilogue: C/D layout col=lane&15, row=quad*4+reg ----
    float* obase = out + (((size_t)b * 128 + h) * 128) * 256 + fh * 128;
#pragma unroll
    for (int mi = 0; mi < 4; ++mi) {
        int wrow = wm_ * 64 + mi * 16 + quad * 4;
#pragma unroll
        for (int ni = 0; ni < 4; ++ni) {
            int f = wn_ * 64 + ni * 16 + lrow;
            f32x4 v = acc[mi][ni];
#pragma unroll
            for (int r = 0; r < 4; ++r) {
                obase[(size_t)(wrow + r) * 256 + f] = v[r];
            }
        }
    }
}

extern "C" void kernel_launch(void* const* d_in, const int* in_sizes, int n_in,
                              void* d_out, int out_size, void* d_ws, size_t ws_size,
                              hipStream_t stream) {
    const float* x     = (const float*)d_in[0];   // [8,128,128,256]
    const float* style = (const float*)d_in[1];   // [8,1,1,256]
    const float* kern  = (const float*)d_in[2];   // [3,3,256,256]
    float* out = (float*)d_out;                   // [8,128,128,256]

    ushort* xbf  = (ushort*)d_ws;                              // 64 MiB bf16
    ushort* wmod = xbf + (size_t)NB * NH * NW * NC;            // 9 MiB bf16

    k_cvt<<<(NB * NH * NW * NC) / (256 * 8), 256, 0, stream>>>(x, xbf);
    k_modw<<<NB * NF, 256, 0, stream>>>(kern, style, wmod);
    k_conv<<<NB * NH * 2, 256, 0, stream>>>(xbf, wmod, out);
}